// Round 1
// baseline (1187.574 us; speedup 1.0000x reference)
//
#include <hip/hip_runtime.h>
#include <cstdint>
#include <cstddef>

#define B_ 4
#define C_ 256
#define N_ 4096
#define BN_TOT (B_ * N_)   // 16384

// ---------------------------------------------------------------------------
// K1: inverse L2 norms over channel dim for both tensors.
// idx in [0, 2*B*N): tensor 0 = xp, tensor 1 = xq.
// ---------------------------------------------------------------------------
__global__ __launch_bounds__(256) void norms_kernel(const float* __restrict__ xp,
                                                    const float* __restrict__ xq,
                                                    float* __restrict__ invp,
                                                    float* __restrict__ invq) {
  int idx = blockIdx.x * 256 + threadIdx.x;
  int tensor = idx >> 14;      // / 16384
  int rem = idx & 16383;
  const float* p = (tensor ? xq : xp) + (size_t)(rem >> 12) * C_ * N_ + (rem & 4095);
  float ss = 0.f;
#pragma unroll 8
  for (int ch = 0; ch < C_; ++ch) {
    float v = p[(size_t)ch * N_];
    ss = fmaf(v, v, ss);
  }
  float inv = 1.0f / fmaxf(sqrtf(ss), 1e-12f);
  (tensor ? invq : invp)[rem] = inv;
}

// ---------------------------------------------------------------------------
// K2: fp32 GEMM C[i][j] = sum_c A[c][i]*B[c][j] (both K-major), fused epilogue:
//   e = exp(alpha * invp[i] * invq[j] * dot) -> e_out (xc_o_q region)
//   rowsum[i] += sum_j e ; colsum[j] += sum_i e   (LDS reduce + global atomics)
// Tile 128x128, BK=8, 256 threads, 8x8 per thread.
// ---------------------------------------------------------------------------
#define BM 128
#define BKK 8
__global__ __launch_bounds__(256) void gemm_exp_kernel(const float* __restrict__ xp,
                                                       const float* __restrict__ xq,
                                                       const float* __restrict__ alpha_p,
                                                       const float* __restrict__ invp,
                                                       const float* __restrict__ invq,
                                                       float* __restrict__ e_out,
                                                       float* __restrict__ rowsum,
                                                       float* __restrict__ colsum) {
  __shared__ float As[BKK][BM];
  __shared__ float Bs[BKK][BM];
  __shared__ float redr[BM];
  __shared__ float redc[BM];

  const int b = blockIdx.z;
  const int i0 = blockIdx.y * BM;
  const int j0 = blockIdx.x * BM;
  const int tid = threadIdx.x;
  const int tx = tid & 15;
  const int ty = tid >> 4;

  const float* A = xp + (size_t)b * C_ * N_;
  const float* Bm = xq + (size_t)b * C_ * N_;

  const int lrow = tid >> 5;         // 0..7
  const int lcol = (tid & 31) << 2;  // 0..124

  float acc[8][8];
#pragma unroll
  for (int r = 0; r < 8; ++r)
#pragma unroll
    for (int c2 = 0; c2 < 8; ++c2) acc[r][c2] = 0.f;

  for (int k0 = 0; k0 < C_; k0 += BKK) {
    float4 av = *(const float4*)&A[(size_t)(k0 + lrow) * N_ + i0 + lcol];
    float4 bv = *(const float4*)&Bm[(size_t)(k0 + lrow) * N_ + j0 + lcol];
    __syncthreads();
    *(float4*)&As[lrow][lcol] = av;
    *(float4*)&Bs[lrow][lcol] = bv;
    __syncthreads();
#pragma unroll
    for (int kk = 0; kk < BKK; ++kk) {
      float a[8], bb[8];
      *(float4*)&a[0] = *(float4*)&As[kk][ty * 8];
      *(float4*)&a[4] = *(float4*)&As[kk][ty * 8 + 4];
      *(float4*)&bb[0] = *(float4*)&Bs[kk][tx * 8];
      *(float4*)&bb[4] = *(float4*)&Bs[kk][tx * 8 + 4];
#pragma unroll
      for (int r = 0; r < 8; ++r)
#pragma unroll
        for (int c2 = 0; c2 < 8; ++c2) acc[r][c2] = fmaf(a[r], bb[c2], acc[r][c2]);
    }
  }

  // epilogue
  if (tid < BM) { redr[tid] = 0.f; redc[tid] = 0.f; }
  __syncthreads();

  const float al = alpha_p[0];
  const int iBase = i0 + ty * 8;
  const int jBase = j0 + tx * 8;
  float invj[8];
#pragma unroll
  for (int c2 = 0; c2 < 8; ++c2) invj[c2] = invq[b * N_ + jBase + c2] * al;
  float csum[8];
#pragma unroll
  for (int c2 = 0; c2 < 8; ++c2) csum[c2] = 0.f;

#pragma unroll
  for (int r = 0; r < 8; ++r) {
    const int i = iBase + r;
    const float ivi = invp[b * N_ + i];
    float rs = 0.f;
    float ev[8];
#pragma unroll
    for (int c2 = 0; c2 < 8; ++c2) {
      float e = __expf(ivi * invj[c2] * acc[r][c2]);
      ev[c2] = e;
      rs += e;
      csum[c2] += e;
    }
    float* dst = e_out + (size_t)(b * N_ + i) * N_ + jBase;
    *(float4*)dst = make_float4(ev[0], ev[1], ev[2], ev[3]);
    *(float4*)(dst + 4) = make_float4(ev[4], ev[5], ev[6], ev[7]);
    atomicAdd(&redr[ty * 8 + r], rs);
  }
#pragma unroll
  for (int c2 = 0; c2 < 8; ++c2) atomicAdd(&redc[tx * 8 + c2], csum[c2]);
  __syncthreads();
  if (tid < BM) {
    atomicAdd(&rowsum[b * N_ + i0 + tid], redr[tid]);
    atomicAdd(&colsum[b * N_ + j0 + tid], redc[tid]);
  }
}

// ---------------------------------------------------------------------------
// K3: in-place reciprocal of row/col sums (2*B*N contiguous floats).
// ---------------------------------------------------------------------------
__global__ __launch_bounds__(256) void recip_kernel(float* __restrict__ v) {
  int idx = blockIdx.x * 256 + threadIdx.x;
  v[idx] = 1.0f / v[idx];
}

// ---------------------------------------------------------------------------
// K4: finalize x_c = e*e*invr[i]*invc[j], in place over the e buffer (xc_o_q),
// plus transposed write into xc_o_p via LDS 64x64 tile.
// ---------------------------------------------------------------------------
__global__ __launch_bounds__(256) void finalize_kernel(float* __restrict__ eq,
                                                       float* __restrict__ outp,
                                                       const float* __restrict__ invr,
                                                       const float* __restrict__ invc) {
  __shared__ float t[64][65];
  const int b = blockIdx.z;
  const int i0 = blockIdx.y * 64;
  const int j0 = blockIdx.x * 64;
  const int tid = threadIdx.x;
  const int tr = tid >> 4;          // 0..15
  const int tc = (tid & 15) << 2;   // 0..60

  float ic0 = invc[b * N_ + j0 + tc + 0];
  float ic1 = invc[b * N_ + j0 + tc + 1];
  float ic2 = invc[b * N_ + j0 + tc + 2];
  float ic3 = invc[b * N_ + j0 + tc + 3];

  const size_t basq = (size_t)(b * N_ + i0) * N_ + j0;
#pragma unroll
  for (int rg = 0; rg < 4; ++rg) {
    const int li = rg * 16 + tr;
    const float ir = invr[b * N_ + i0 + li];
    float4 e4 = *(const float4*)(eq + basq + (size_t)li * N_ + tc);
    float4 v;
    v.x = e4.x * e4.x * ir * ic0;
    v.y = e4.y * e4.y * ir * ic1;
    v.z = e4.z * e4.z * ir * ic2;
    v.w = e4.w * e4.w * ir * ic3;
    *(float4*)(eq + basq + (size_t)li * N_ + tc) = v;
    t[tc + 0][li] = v.x;
    t[tc + 1][li] = v.y;
    t[tc + 2][li] = v.z;
    t[tc + 3][li] = v.w;
  }
  __syncthreads();
  const size_t basp = (size_t)(b * N_ + j0) * N_ + i0;
#pragma unroll
  for (int cg = 0; cg < 4; ++cg) {
    const int lj = cg * 16 + tr;
    float4 v;
    v.x = t[lj][tc + 0];
    v.y = t[lj][tc + 1];
    v.z = t[lj][tc + 2];
    v.w = t[lj][tc + 3];
    *(float4*)(outp + basp + (size_t)lj * N_ + tc) = v;
  }
}

// ---------------------------------------------------------------------------
// K5/K6: per-row top-3 scan. One wave per row, 4 rows per block.
// mat: [B*N][N]; out: [B][3][N] at out[b*3*N + k*N + r].
// Branchless sorted-triple insert: 5 min/max ops.
// ---------------------------------------------------------------------------
__device__ __forceinline__ void top3_insert(float& a0, float& a1, float& a2, float x) {
  float m0 = fmaxf(a0, x);
  float c0 = fminf(a0, x);
  float m1 = fmaxf(a1, c0);
  float c1 = fminf(a1, c0);
  float m2 = fmaxf(a2, c1);
  a0 = m0; a1 = m1; a2 = m2;
}

__global__ __launch_bounds__(256) void row_top3_kernel(const float* __restrict__ mat,
                                                       float* __restrict__ out) {
  const int wave = threadIdx.x >> 6;
  const int lane = threadIdx.x & 63;
  const int row = blockIdx.x * 4 + wave;   // 0..16383
  const int b = row >> 12;
  const int r = row & 4095;
  const float* p = mat + (size_t)row * N_;

  float a0 = -1e30f, a1 = -1e30f, a2 = -1e30f;
#pragma unroll 4
  for (int it = 0; it < 16; ++it) {
    float4 v = *(const float4*)(p + it * 256 + lane * 4);
    top3_insert(a0, a1, a2, v.x);
    top3_insert(a0, a1, a2, v.y);
    top3_insert(a0, a1, a2, v.z);
    top3_insert(a0, a1, a2, v.w);
  }
#pragma unroll
  for (int mask = 1; mask <= 32; mask <<= 1) {
    float b0 = __shfl_xor(a0, mask);
    float b1 = __shfl_xor(a1, mask);
    float b2 = __shfl_xor(a2, mask);
    top3_insert(a0, a1, a2, b0);
    top3_insert(a0, a1, a2, b1);
    top3_insert(a0, a1, a2, b2);
  }
  if (lane == 0) {
    out[(b * 3 + 0) * N_ + r] = a0;
    out[(b * 3 + 1) * N_ + r] = a1;
    out[(b * 3 + 2) * N_ + r] = a2;
  }
}

// ---------------------------------------------------------------------------
extern "C" void kernel_launch(void* const* d_in, const int* in_sizes, int n_in,
                              void* d_out, int out_size, void* d_ws, size_t ws_size,
                              hipStream_t stream) {
  const float* xp = (const float*)d_in[0];
  const float* xq = (const float*)d_in[1];
  const float* alpha = (const float*)d_in[2];

  float* o = (float*)d_out;
  float* valp = o;                               // [4,3,64,64]   = 49152
  float* valq = o + 49152;                       // [4,3,64,64]   = 49152
  float* xcp = o + 98304;                        // [4,4096,64,64]= 67108864
  float* xcq = o + 98304 + 67108864;             // [4,4096,64,64]

  float* wsf = (float*)d_ws;
  float* invp = wsf;                  // 16384
  float* invq = wsf + 16384;          // 16384
  float* rowsum = wsf + 32768;        // 16384
  float* colsum = wsf + 49152;        // 16384

  hipMemsetAsync(rowsum, 0, (size_t)2 * BN_TOT * sizeof(float), stream);

  norms_kernel<<<2 * BN_TOT / 256, 256, 0, stream>>>(xp, xq, invp, invq);

  gemm_exp_kernel<<<dim3(N_ / BM, N_ / BM, B_), 256, 0, stream>>>(
      xp, xq, alpha, invp, invq, xcq, rowsum, colsum);

  recip_kernel<<<2 * BN_TOT / 256, 256, 0, stream>>>(rowsum);  // rowsum+colsum contiguous

  finalize_kernel<<<dim3(N_ / 64, N_ / 64, B_), 256, 0, stream>>>(xcq, xcp, rowsum, colsum);

  row_top3_kernel<<<BN_TOT / 4, 256, 0, stream>>>(xcq, valp);  // rows of x_c  -> valp
  row_top3_kernel<<<BN_TOT / 4, 256, 0, stream>>>(xcp, valq);  // cols of x_c  -> valq
}